// Round 3
// baseline (200.967 us; speedup 1.0000x reference)
//
#include <hip/hip_runtime.h>
#include <hip/hip_bf16.h>

typedef short s16x8 __attribute__((ext_vector_type(8)));
typedef float fp32x4 __attribute__((ext_vector_type(4)));

#define D_DIM 4096
#define OUT_STRIDE 65536  // M*B = 1024*64

__device__ __forceinline__ unsigned int f2bf(float f) {
    unsigned int u = __float_as_uint(f);
    u += 0x7FFFu + ((u >> 16) & 1u);
    return u >> 16;
}

__device__ __forceinline__ void gload16(const void* gp, void* lp) {
    __builtin_amdgcn_global_load_lds(
        (const __attribute__((address_space(1))) void*)gp,
        (__attribute__((address_space(3))) void*)lp, 16, 0, 0);
}

// One block per (g,e): normalize V[g,e,:,:] over t, write bf16 B^T pre-swizzled:
// Bn[(g*1024 + e*64 + b)*128 + k], 16B-chunk swizzle: chunk ^= (b&7)
__global__ __launch_bounds__(256) void vnorm_kernel(const float* __restrict__ V,
                                                    unsigned short* __restrict__ Bn) {
    const int blk = blockIdx.x;          // g*16 + e
    const int tid = threadIdx.x;
    const float* Vt = V + (size_t)blk * 8192;   // [t=128][b=64] fp32
    __shared__ float tile[8192];
    __shared__ float part[256];
    __shared__ float rnorm[64];

    for (int i = tid; i < 2048; i += 256)
        ((float4*)tile)[i] = ((const float4*)Vt)[i];
    __syncthreads();

    {
        int b = tid & 63, q = tid >> 6;
        float s = 0.f;
        for (int t = q; t < 128; t += 4) { float v = tile[t * 64 + b]; s += v * v; }
        part[tid] = s;
    }
    __syncthreads();
    if (tid < 64) {
        float tot = part[tid] + part[tid + 64] + part[tid + 128] + part[tid + 192];
        rnorm[tid] = rsqrtf(tot);
    }
    __syncthreads();

    unsigned short* rowbase = Bn + (size_t)blk * 64 * 128;  // row j = blk*64 + b
    for (int iter = 0; iter < 4; ++iter) {
        int idx = iter * 256 + tid;
        int b = idx >> 4, k8 = idx & 15;     // k8 = 16B chunk (8 bf16)
        float rn = rnorm[b];
        unsigned int w[4];
        int tb = k8 * 8;
        #pragma unroll
        for (int j = 0; j < 4; ++j) {
            float v0 = tile[(tb + 2 * j) * 64 + b] * rn;
            float v1 = tile[(tb + 2 * j + 1) * 64 + b] * rn;
            w[j] = f2bf(v0) | (f2bf(v1) << 16);
        }
        int chunk = k8 ^ (b & 7);            // 16B-chunk XOR swizzle
        uint4* dst = (uint4*)(rowbase + b * 128) + chunk;
        *dst = make_uint4(w[0], w[1], w[2], w[3]);
    }
}

// grid: (mblk=N/128, g=64), 512 threads / 8 waves. Block owns 128 rows x all
// 1024 cols of tile g. A gathered from x once, resident; B double-buffered
// over the 8 n-tiles with counted-vmcnt pipeline; NT stores for output.
__global__ __launch_bounds__(512) void gemm_kernel(const float* __restrict__ x,
                                                   const unsigned short* __restrict__ Bn,
                                                   float* __restrict__ out) {
    const int m0 = blockIdx.x * 128;
    const int g = blockIdx.y;
    const int tid = threadIdx.x;
    const int lane = tid & 63, wid = tid >> 6;

    __shared__ __align__(16) unsigned short Alds[16384];      // 32KB [row128][k128] swz
    __shared__ __align__(16) unsigned short Blds[2][16384];   // 2x32KB [j128][k128] swz

    // ---- prologue: gather+convert A from x (swizzled ds_write) ----
    {
        int t4 = tid & 31;                   // float4 index along k
        int rg = tid >> 5;                   // 0..15
        int k0 = t4 * 4;
        int idx = (g < 32) ? (g * 128 + k0)
                           : ((k0 >> 5) * 1024 + (g - 32) * 32 + (k0 & 31));
        const float* xb = x + idx;
        #pragma unroll
        for (int it = 0; it < 8; ++it) {
            int i = it * 16 + rg;
            float4 v = *(const float4*)(xb + (size_t)(m0 + i) * D_DIM);
            unsigned int lo = f2bf(v.x) | (f2bf(v.y) << 16);
            unsigned int hi = f2bf(v.z) | (f2bf(v.w) << 16);
            int slot = t4 ^ ((i & 7) << 1);  // 8B-slot XOR == byte ^ ((i&7)<<4)
            *(uint2*)((char*)Alds + i * 256 + slot * 8) = make_uint2(lo, hi);
        }
    }
    // ---- prologue: stage B[0] (linear async copy, swizzle pre-baked) ----
    const char* Bpanel = (const char*)(Bn + (size_t)g * 1024 * 128);
    #pragma unroll
    for (int it = 0; it < 4; ++it)
        gload16(Bpanel + it * 8192 + tid * 16, (char*)Blds[0] + it * 8192 + tid * 16);
    __syncthreads();  // drains vmcnt + lgkmcnt once (prologue only)

    // wave (wr,wc): 64x32 sub-tile. 4 m-frags x 2 n-frags x 4 k-steps = 32 MFMA.
    const int wr = wid >> 2, wc = wid & 3;
    const int r = lane & 15;
    const int kq16 = (lane >> 4) << 4;       // k-quarter byte offset
    const int swz = (lane & 7) << 4;         // row&7 == lane&7 for all frags
    const char* Ab = (const char*)Alds + (wr * 64 + r) * 256;
    const int col = lane & 15, rq = lane >> 4;

    for (int t = 0; t < 8; ++t) {
        const char* Bcur = (const char*)Blds[t & 1];
        // issue next B stage (4 loads, stays in flight across compute+stores)
        if (t < 7) {
            const char* src = Bpanel + (size_t)(t + 1) * 32768;
            char* dst = (char*)Blds[(t + 1) & 1];
            #pragma unroll
            for (int it = 0; it < 4; ++it)
                gload16(src + it * 8192 + tid * 16, dst + it * 8192 + tid * 16);
        }
        asm volatile("" ::: "memory");

        fp32x4 acc[4][2];
        #pragma unroll
        for (int mi = 0; mi < 4; ++mi) {
            acc[mi][0] = (fp32x4){0.f, 0.f, 0.f, 0.f};
            acc[mi][1] = (fp32x4){0.f, 0.f, 0.f, 0.f};
        }
        const char* Bb = Bcur + (wc * 32 + r) * 256;
        #pragma unroll
        for (int kk = 0; kk < 4; ++kk) {
            int kb = (kk * 64 + kq16) ^ swz;
            s16x8 a[4], b[2];
            #pragma unroll
            for (int mi = 0; mi < 4; ++mi) a[mi] = *(const s16x8*)(Ab + mi * 16 * 256 + kb);
            #pragma unroll
            for (int ni = 0; ni < 2; ++ni) b[ni] = *(const s16x8*)(Bb + ni * 16 * 256 + kb);
            #pragma unroll
            for (int mi = 0; mi < 4; ++mi)
                #pragma unroll
                for (int ni = 0; ni < 2; ++ni)
                    acc[mi][ni] = __builtin_amdgcn_mfma_f32_16x16x32_bf16(
                        a[mi], b[ni], acc[mi][ni], 0, 0, 0);
        }

        // ---- epilogue: NT stores (32/thread). C/D: col=lane&15, row=rq*4+e ----
        float* obase = out + (size_t)(g * 1024 + t * 128 + wc * 32 + col);
        #pragma unroll
        for (int mi = 0; mi < 4; ++mi) {
            #pragma unroll
            for (int e = 0; e < 4; ++e) {
                int row = m0 + wr * 64 + mi * 16 + rq * 4 + e;
                float* p = obase + (size_t)row * OUT_STRIDE;
                __builtin_nontemporal_store(acc[mi][0][e], p);
                __builtin_nontemporal_store(acc[mi][1][e], p + 16);
            }
        }

        if (t < 7) {
            // wait for the 4 B[t+1] loads (older than the 32 stores): <=32 left
            asm volatile("s_waitcnt vmcnt(32)" ::: "memory");
            __builtin_amdgcn_s_barrier();
            asm volatile("" ::: "memory");
        }
    }
}

extern "C" void kernel_launch(void* const* d_in, const int* in_sizes, int n_in,
                              void* d_out, int out_size, void* d_ws, size_t ws_size,
                              hipStream_t stream) {
    const float* x = (const float*)d_in[0];
    const float* V = (const float*)d_in[1];
    // d_in[2] (tile_idx) unused: index pattern computed analytically in-kernel.
    float* out = (float*)d_out;
    unsigned short* Bn = (unsigned short*)d_ws;  // 16.8 MB scratch

    const int N = in_sizes[0] / D_DIM;           // 2048
    const int nmb = N / 128;                     // 16

    vnorm_kernel<<<1024, 256, 0, stream>>>(V, Bn);
    gemm_kernel<<<dim3(nmb, 64), 512, 0, stream>>>(x, Bn, out);
}

// Round 4
// 180.552 us; speedup vs baseline: 1.1131x; 1.1131x over previous
//
#include <hip/hip_runtime.h>
#include <hip/hip_bf16.h>

typedef short s16x8 __attribute__((ext_vector_type(8)));
typedef float fp32x4 __attribute__((ext_vector_type(4)));

#define D_DIM 4096
#define OUT_STRIDE 65536  // M*B = 1024*64

__device__ __forceinline__ unsigned int f2bf(float f) {
    unsigned int u = __float_as_uint(f);
    u += 0x7FFFu + ((u >> 16) & 1u);
    return u >> 16;
}

__device__ __forceinline__ void gload16(const void* gp, void* lp) {
    __builtin_amdgcn_global_load_lds(
        (const __attribute__((address_space(1))) void*)gp,
        (__attribute__((address_space(3))) void*)lp, 16, 0, 0);
}

// One block per (g,e): normalize V[g,e,:,:] over t, write bf16 B^T pre-swizzled:
// Bn[(g*1024 + e*64 + b)*128 + k], 16B-chunk swizzle: chunk ^= (b&7)
__global__ __launch_bounds__(256) void vnorm_kernel(const float* __restrict__ V,
                                                    unsigned short* __restrict__ Bn) {
    const int blk = blockIdx.x;          // g*16 + e
    const int tid = threadIdx.x;
    const float* Vt = V + (size_t)blk * 8192;   // [t=128][b=64] fp32
    __shared__ float tile[8192];
    __shared__ float part[256];
    __shared__ float rnorm[64];

    for (int i = tid; i < 2048; i += 256)
        ((float4*)tile)[i] = ((const float4*)Vt)[i];
    __syncthreads();

    {
        int b = tid & 63, q = tid >> 6;
        float s = 0.f;
        for (int t = q; t < 128; t += 4) { float v = tile[t * 64 + b]; s += v * v; }
        part[tid] = s;
    }
    __syncthreads();
    if (tid < 64) {
        float tot = part[tid] + part[tid + 64] + part[tid + 128] + part[tid + 192];
        rnorm[tid] = rsqrtf(tot);
    }
    __syncthreads();

    unsigned short* rowbase = Bn + (size_t)blk * 64 * 128;  // row j = blk*64 + b
    for (int iter = 0; iter < 4; ++iter) {
        int idx = iter * 256 + tid;
        int b = idx >> 4, k8 = idx & 15;     // k8 = 16B chunk (8 bf16)
        float rn = rnorm[b];
        unsigned int w[4];
        int tb = k8 * 8;
        #pragma unroll
        for (int j = 0; j < 4; ++j) {
            float v0 = tile[(tb + 2 * j) * 64 + b] * rn;
            float v1 = tile[(tb + 2 * j + 1) * 64 + b] * rn;
            w[j] = f2bf(v0) | (f2bf(v1) << 16);
        }
        int chunk = k8 ^ (b & 7);            // 16B-chunk XOR swizzle
        uint4* dst = (uint4*)(rowbase + b * 128) + chunk;
        *dst = make_uint4(w[0], w[1], w[2], w[3]);
    }
}

// grid: (mblk=N/128, g=64), 512 threads / 8 waves. Block owns 128 rows x all
// 1024 cols of tile g. A gathered from x once, resident; B double-buffered
// over the 8 n-tiles (counted vmcnt). Epilogue: acc -> LDS (reusing the dead
// B buffer) -> float4 read-back -> dwordx4 stores = full 128B lines per inst.
__global__ __launch_bounds__(512) void gemm_kernel(const float* __restrict__ x,
                                                   const unsigned short* __restrict__ Bn,
                                                   float* __restrict__ out) {
    const int m0 = blockIdx.x * 128;
    const int g = blockIdx.y;
    const int tid = threadIdx.x;
    const int lane = tid & 63, wid = tid >> 6;
    const int wr = wid >> 2, wc = wid & 3;

    __shared__ __align__(16) unsigned short Alds[16384];      // 32KB [row128][k128] swz
    __shared__ __align__(16) unsigned short Blds[2][16384];   // 2x32KB [j128][k128] swz

    // ---- prologue: gather+convert A from x (swizzled ds_write) ----
    {
        int t4 = tid & 31;                   // float4 index along k
        int rg = tid >> 5;                   // 0..15
        int k0 = t4 * 4;
        int idx = (g < 32) ? (g * 128 + k0)
                           : ((k0 >> 5) * 1024 + (g - 32) * 32 + (k0 & 31));
        const float* xb = x + idx;
        #pragma unroll
        for (int it = 0; it < 8; ++it) {
            int i = it * 16 + rg;
            float4 v = *(const float4*)(xb + (size_t)(m0 + i) * D_DIM);
            unsigned int lo = f2bf(v.x) | (f2bf(v.y) << 16);
            unsigned int hi = f2bf(v.z) | (f2bf(v.w) << 16);
            int slot = t4 ^ ((i & 7) << 1);  // 8B-slot XOR == byte ^ ((i&7)<<4)
            *(uint2*)((char*)Alds + i * 256 + slot * 8) = make_uint2(lo, hi);
        }
    }
    // ---- prologue: stage B[0] (linear async copy, swizzle pre-baked) ----
    const char* Bpanel = (const char*)(Bn + (size_t)g * 1024 * 128);
    #pragma unroll
    for (int it = 0; it < 4; ++it)
        gload16(Bpanel + it * 8192 + tid * 16, (char*)Blds[0] + it * 8192 + tid * 16);
    __syncthreads();  // prologue drain (only full drain in the kernel)

    const int r16 = lane & 15, rq = lane >> 4;
    const int kq16 = rq << 4;                // k-quarter byte offset
    const int swz = (lane & 7) << 4;         // LDS read swizzle (matches staging)
    const char* Ab = (const char*)Alds + (wr * 64 + r16) * 256;

    // Epilogue XP addressing: XP = float[64][128], byte swizzle: bit6 ^= (row&4)<<4.
    const int colb0 = (wc * 32 + r16) << 2;  // ni=0 col byte offset
    const int wsz = (rq & 1) << 6;           // == (row&4)<<4 for rows rq*4+e

    int cur = 0;
    for (int t = 0; t < 8; ++t) {
        // issue next B stage (4 loads; stay in flight across compute+epilogue)
        if (t < 7) {
            const char* src = Bpanel + (size_t)(t + 1) * 32768;
            char* dst = (char*)Blds[cur ^ 1];
            #pragma unroll
            for (int it = 0; it < 4; ++it)
                gload16(src + it * 8192 + tid * 16, dst + it * 8192 + tid * 16);
        }
        asm volatile("" ::: "memory");

        fp32x4 acc[4][2];
        #pragma unroll
        for (int mi = 0; mi < 4; ++mi) {
            acc[mi][0] = (fp32x4){0.f, 0.f, 0.f, 0.f};
            acc[mi][1] = (fp32x4){0.f, 0.f, 0.f, 0.f};
        }
        const char* Bb = (const char*)Blds[cur] + (wc * 32 + r16) * 256;
        #pragma unroll
        for (int kk = 0; kk < 4; ++kk) {
            int kb = (kk * 64 + kq16) ^ swz;
            s16x8 a[4], b[2];
            #pragma unroll
            for (int mi = 0; mi < 4; ++mi) a[mi] = *(const s16x8*)(Ab + mi * 16 * 256 + kb);
            #pragma unroll
            for (int ni = 0; ni < 2; ++ni) b[ni] = *(const s16x8*)(Bb + ni * 16 * 256 + kb);
            #pragma unroll
            for (int mi = 0; mi < 4; ++mi)
                #pragma unroll
                for (int ni = 0; ni < 2; ++ni)
                    acc[mi][ni] = __builtin_amdgcn_mfma_f32_16x16x32_bf16(
                        a[mi], b[ni], acc[mi][ni], 0, 0, 0);
        }

        // Blds[cur] is dead after compute reads -> reuse as 32KB f32 transpose buf.
        char* XP = (char*)Blds[cur];
        asm volatile("s_waitcnt lgkmcnt(0)" ::: "memory");
        __builtin_amdgcn_s_barrier();

        #pragma unroll
        for (int r = 0; r < 2; ++r) {
            if (wr == r) {
                #pragma unroll
                for (int mi = 0; mi < 4; ++mi) {
                    char* rowb = XP + (mi * 16 + rq * 4) * 512;
                    #pragma unroll
                    for (int ni = 0; ni < 2; ++ni) {
                        char* p = rowb + ((colb0 + (ni << 6)) ^ wsz);
                        #pragma unroll
                        for (int e = 0; e < 4; ++e)
                            *(float*)(p + e * 512) = acc[mi][ni][e];
                    }
                }
            }
            asm volatile("s_waitcnt lgkmcnt(0)" ::: "memory");
            __builtin_amdgcn_s_barrier();

            // all 512 threads: float4 read-back + full-line dwordx4 stores
            float* orow = out + (size_t)(m0 + r * 64) * OUT_STRIDE + g * 1024 + t * 128;
            #pragma unroll
            for (int q = 0; q < 4; ++q) {
                int flat = q * 512 + tid;
                int row = flat >> 5, c4 = flat & 31;
                fp32x4 v = *(const fp32x4*)(XP + row * 512 + ((c4 << 4) ^ ((row & 4) << 4)));
                *(fp32x4*)(orow + (size_t)row * OUT_STRIDE + c4 * 4) = v;
            }
            asm volatile("s_waitcnt lgkmcnt(0)" ::: "memory");
            __builtin_amdgcn_s_barrier();
        }

        if (t < 7) {
            // 4 prefetch loads are older than the 8 stores: vmcnt(8) => loads done
            asm volatile("s_waitcnt vmcnt(8)" ::: "memory");
            __builtin_amdgcn_s_barrier();
        }
        cur ^= 1;
    }
}

extern "C" void kernel_launch(void* const* d_in, const int* in_sizes, int n_in,
                              void* d_out, int out_size, void* d_ws, size_t ws_size,
                              hipStream_t stream) {
    const float* x = (const float*)d_in[0];
    const float* V = (const float*)d_in[1];
    // d_in[2] (tile_idx) unused: index pattern computed analytically in-kernel.
    float* out = (float*)d_out;
    unsigned short* Bn = (unsigned short*)d_ws;  // 16.8 MB scratch

    const int N = in_sizes[0] / D_DIM;           // 2048
    const int nmb = N / 128;                     // 16

    vnorm_kernel<<<1024, 256, 0, stream>>>(V, Bn);
    gemm_kernel<<<dim3(nmb, 64), 512, 0, stream>>>(x, Bn, out);
}

// Round 5
// 148.781 us; speedup vs baseline: 1.3508x; 1.2135x over previous
//
#include <hip/hip_runtime.h>
#include <hip/hip_bf16.h>

typedef short s16x8 __attribute__((ext_vector_type(8)));
typedef float f32x16 __attribute__((ext_vector_type(16)));

#define D_DIM 4096
#define OUT_STRIDE 65536  // M*B = 1024*64

__device__ __forceinline__ unsigned int f2bf(float f) {
    unsigned int u = __float_as_uint(f);
    u += 0x7FFFu + ((u >> 16) & 1u);
    return u >> 16;
}
__device__ __forceinline__ unsigned int pk2(float a, float b) {
    return f2bf(a) | (f2bf(b) << 16);
}

__device__ __forceinline__ void gload16(const void* gp, void* lp) {
    __builtin_amdgcn_global_load_lds(
        (const __attribute__((address_space(1))) void*)gp,
        (__attribute__((address_space(3))) void*)lp, 16, 0, 0);
}

// One block per (g,e): normalize V[g,e,:,:] over t, write bf16 B^T pre-swizzled:
// Bn[(g*1024 + e*64 + b)*128 + k], 16B-chunk swizzle: chunk ^= (b&7)
__global__ __launch_bounds__(256) void vnorm_kernel(const float* __restrict__ V,
                                                    unsigned short* __restrict__ Bn) {
    const int blk = blockIdx.x;          // g*16 + e
    const int tid = threadIdx.x;
    const float* Vt = V + (size_t)blk * 8192;   // [t=128][b=64] fp32
    __shared__ float tile[8192];
    __shared__ float part[256];
    __shared__ float rnorm[64];

    for (int i = tid; i < 2048; i += 256)
        ((float4*)tile)[i] = ((const float4*)Vt)[i];
    __syncthreads();

    {
        int b = tid & 63, q = tid >> 6;
        float s = 0.f;
        for (int t = q; t < 128; t += 4) { float v = tile[t * 64 + b]; s += v * v; }
        part[tid] = s;
    }
    __syncthreads();
    if (tid < 64) {
        float tot = part[tid] + part[tid + 64] + part[tid + 128] + part[tid + 192];
        rnorm[tid] = rsqrtf(tot);
    }
    __syncthreads();

    unsigned short* rowbase = Bn + (size_t)blk * 64 * 128;  // row j = blk*64 + b
    for (int iter = 0; iter < 4; ++iter) {
        int idx = iter * 256 + tid;
        int b = idx >> 4, k8 = idx & 15;     // k8 = 16B chunk (8 bf16)
        float rn = rnorm[b];
        unsigned int w[4];
        int tb = k8 * 8;
        #pragma unroll
        for (int j = 0; j < 4; ++j) {
            float v0 = tile[(tb + 2 * j) * 64 + b] * rn;
            float v1 = tile[(tb + 2 * j + 1) * 64 + b] * rn;
            w[j] = pk2(v0, v1);
        }
        int chunk = k8 ^ (b & 7);            // 16B-chunk XOR swizzle
        uint4* dst = (uint4*)(rowbase + b * 128) + chunk;
        *dst = make_uint4(w[0], w[1], w[2], w[3]);
    }
}

// grid: (g=64, mblk=N/128), 512 threads / 8 waves, 2 blocks/CU (64KB LDS).
// Wave (wr,wc): 32 rows x 64 cols via 2x mfma_32x32x16, K=128 in 8 steps.
// A: registers, loaded direct from x (k-runs of 8 are contiguous in x for both
// horiz and vert tiles). B: LDS double-buffer, counted-vmcnt prefetch.
// Stores: per acc register = 2 full 128B lines (C/D col=lane&31).
__global__ __launch_bounds__(512, 4) void gemm_kernel(const float* __restrict__ x,
                                                      const unsigned short* __restrict__ Bn,
                                                      float* __restrict__ out) {
    const int g = blockIdx.x;
    const int m0 = blockIdx.y * 128;
    const int tid = threadIdx.x;
    const int lane = tid & 63, wid = tid >> 6;
    const int wr = wid >> 1, wc = wid & 1;   // 4 row-waves x 2 col-waves
    const int jl = lane & 31, hi = lane >> 5;

    __shared__ __align__(16) unsigned short Blds[2][16384];  // 2x32KB [j128][k128] swz

    // ---- prologue: A -> registers (gather from x, convert to bf16) ----
    s16x8 afrag[8];
    {
        const float* xrow = x + (size_t)(m0 + wr * 32 + jl) * D_DIM;
        #pragma unroll
        for (int ks = 0; ks < 8; ++ks) {
            int k0 = ks * 16 + hi * 8;
            int idx = (g < 32) ? (g * 128 + k0)
                               : ((k0 >> 5) * 1024 + (g - 32) * 32 + (k0 & 31));
            float4 v0 = *(const float4*)(xrow + idx);
            float4 v1 = *(const float4*)(xrow + idx + 4);
            union { uint4 u; s16x8 s; } pk;
            pk.u.x = pk2(v0.x, v0.y); pk.u.y = pk2(v0.z, v0.w);
            pk.u.z = pk2(v1.x, v1.y); pk.u.w = pk2(v1.z, v1.w);
            afrag[ks] = pk.s;
        }
    }
    // ---- prologue: stage B[0] (linear async copy, swizzle pre-baked) ----
    const char* Bpanel = (const char*)(Bn + (size_t)g * 1024 * 128);
    #pragma unroll
    for (int it = 0; it < 4; ++it)
        gload16(Bpanel + it * 8192 + tid * 16, (char*)Blds[0] + it * 8192 + tid * 16);
    __syncthreads();

    // B read addressing: row j = wc*64 + ni*32 + jl; swizzled chunk byte =
    // (ks*32 + hi*16) ^ ((jl&7)<<4)
    const int swz = (jl & 7) << 4;
    const int rb0 = (wc * 64 + jl) * 256;        // ni=0 row byte
    const int rb1 = (wc * 64 + 32 + jl) * 256;   // ni=1 row byte

    int cur = 0;
    for (int t = 0; t < 8; ++t) {
        // issue next B tile (4 loads/thread; in flight across compute+stores)
        if (t < 7) {
            const char* src = Bpanel + (size_t)(t + 1) * 32768;
            char* dst = (char*)Blds[cur ^ 1];
            #pragma unroll
            for (int it = 0; it < 4; ++it)
                gload16(src + it * 8192 + tid * 16, dst + it * 8192 + tid * 16);
        }
        asm volatile("" ::: "memory");

        const char* Bb = (const char*)Blds[cur];
        f32x16 acc0 = {0.f}, acc1 = {0.f};
        #pragma unroll
        for (int ks = 0; ks < 8; ++ks) {
            int kb = (ks * 32 + hi * 16) ^ swz;
            s16x8 b0 = *(const s16x8*)(Bb + rb0 + kb);
            s16x8 b1 = *(const s16x8*)(Bb + rb1 + kb);
            acc0 = __builtin_amdgcn_mfma_f32_32x32x16_bf16(afrag[ks], b0, acc0, 0, 0, 0);
            acc1 = __builtin_amdgcn_mfma_f32_32x32x16_bf16(afrag[ks], b1, acc1, 0, 0, 0);
        }

        // ---- stores: each reg covers a full 128B line per half-wave ----
        float* obase = out + (size_t)(m0 + wr * 32 + 4 * hi) * OUT_STRIDE
                     + g * 1024 + t * 128 + wc * 64 + jl;
        #pragma unroll
        for (int reg = 0; reg < 16; ++reg) {
            int row = (reg & 3) + 8 * (reg >> 2);
            float* p = obase + (size_t)row * OUT_STRIDE;
            p[0] = acc0[reg];
            p[32] = acc1[reg];
        }

        if (t < 7) {
            // 4 prefetch loads are older than the 32 stores: vmcnt(32) => loads done
            asm volatile("s_waitcnt vmcnt(32)" ::: "memory");
            __builtin_amdgcn_s_barrier();
        }
        cur ^= 1;
    }
}

extern "C" void kernel_launch(void* const* d_in, const int* in_sizes, int n_in,
                              void* d_out, int out_size, void* d_ws, size_t ws_size,
                              hipStream_t stream) {
    const float* x = (const float*)d_in[0];
    const float* V = (const float*)d_in[1];
    // d_in[2] (tile_idx) unused: index pattern computed analytically in-kernel.
    float* out = (float*)d_out;
    unsigned short* Bn = (unsigned short*)d_ws;  // 16.8 MB scratch

    const int N = in_sizes[0] / D_DIM;           // 2048
    const int nmb = N / 128;                     // 16

    vnorm_kernel<<<1024, 256, 0, stream>>>(V, Bn);
    gemm_kernel<<<dim3(64, nmb), 512, 0, stream>>>(x, Bn, out);
}

// Round 6
// 146.998 us; speedup vs baseline: 1.3671x; 1.0121x over previous
//
#include <hip/hip_runtime.h>
#include <hip/hip_bf16.h>

typedef short s16x8 __attribute__((ext_vector_type(8)));
typedef float f32x16 __attribute__((ext_vector_type(16)));

#define D_DIM 4096
#define OUT_STRIDE 65536  // M*B = 1024*64

__device__ __forceinline__ unsigned int f2bf(float f) {
    unsigned int u = __float_as_uint(f);
    u += 0x7FFFu + ((u >> 16) & 1u);
    return u >> 16;
}
__device__ __forceinline__ unsigned int pk2(float a, float b) {
    return f2bf(a) | (f2bf(b) << 16);
}

__device__ __forceinline__ void gload16(const void* gp, void* lp) {
    __builtin_amdgcn_global_load_lds(
        (const __attribute__((address_space(1))) void*)gp,
        (__attribute__((address_space(3))) void*)lp, 16, 0, 0);
}

// One block per (g,e): normalize V[g,e,:,:] over t, write bf16 B^T pre-swizzled:
// Bn[(g*1024 + e*64 + b)*128 + k], 16B-chunk swizzle: chunk ^= (b&7)
__global__ __launch_bounds__(256) void vnorm_kernel(const float* __restrict__ V,
                                                    unsigned short* __restrict__ Bn) {
    const int blk = blockIdx.x;          // g*16 + e
    const int tid = threadIdx.x;
    const float* Vt = V + (size_t)blk * 8192;   // [t=128][b=64] fp32
    __shared__ float tile[8192];
    __shared__ float part[256];
    __shared__ float rnorm[64];

    for (int i = tid; i < 2048; i += 256)
        ((float4*)tile)[i] = ((const float4*)Vt)[i];
    __syncthreads();

    {
        int b = tid & 63, q = tid >> 6;
        float s = 0.f;
        for (int t = q; t < 128; t += 4) { float v = tile[t * 64 + b]; s += v * v; }
        part[tid] = s;
    }
    __syncthreads();
    if (tid < 64) {
        float tot = part[tid] + part[tid + 64] + part[tid + 128] + part[tid + 192];
        rnorm[tid] = rsqrtf(tot);
    }
    __syncthreads();

    unsigned short* rowbase = Bn + (size_t)blk * 64 * 128;  // row j = blk*64 + b
    for (int iter = 0; iter < 4; ++iter) {
        int idx = iter * 256 + tid;
        int b = idx >> 4, k8 = idx & 15;     // k8 = 16B chunk (8 bf16)
        float rn = rnorm[b];
        unsigned int w[4];
        int tb = k8 * 8;
        #pragma unroll
        for (int j = 0; j < 4; ++j) {
            float v0 = tile[(tb + 2 * j) * 64 + b] * rn;
            float v1 = tile[(tb + 2 * j + 1) * 64 + b] * rn;
            w[j] = pk2(v0, v1);
        }
        int chunk = k8 ^ (b & 7);            // 16B-chunk XOR swizzle
        uint4* dst = (uint4*)(rowbase + b * 128) + chunk;
        *dst = make_uint4(w[0], w[1], w[2], w[3]);
    }
}

// grid: (mblk=N/128 fast, g=64 slow), 512 threads / 8 waves, 2 blocks/CU.
// Wave (wr,wc): 32 rows x 64 cols via 2x mfma_32x32x16, K=128 in 8 steps.
// A: registers, loaded direct from x. B: LDS double-buffer, counted-vmcnt
// prefetch. Stores: nontemporal (don't thrash L3 -> Bn/x stay resident);
// each store inst covers 2 full 128B lines (C/D col=lane&31).
__global__ __launch_bounds__(512, 4) void gemm_kernel(const float* __restrict__ x,
                                                      const unsigned short* __restrict__ Bn,
                                                      float* __restrict__ out) {
    const int m0 = blockIdx.x * 128;
    const int g = blockIdx.y;
    const int tid = threadIdx.x;
    const int lane = tid & 63, wid = tid >> 6;
    const int wr = wid >> 1, wc = wid & 1;   // 4 row-waves x 2 col-waves
    const int jl = lane & 31, hi = lane >> 5;

    __shared__ __align__(16) unsigned short Blds[2][16384];  // 2x32KB [j128][k128] swz

    // ---- prologue: A -> registers (gather from x, convert to bf16) ----
    s16x8 afrag[8];
    {
        const float* xrow = x + (size_t)(m0 + wr * 32 + jl) * D_DIM;
        #pragma unroll
        for (int ks = 0; ks < 8; ++ks) {
            int k0 = ks * 16 + hi * 8;
            int idx = (g < 32) ? (g * 128 + k0)
                               : ((k0 >> 5) * 1024 + (g - 32) * 32 + (k0 & 31));
            float4 v0 = *(const float4*)(xrow + idx);
            float4 v1 = *(const float4*)(xrow + idx + 4);
            union { uint4 u; s16x8 s; } pk;
            pk.u.x = pk2(v0.x, v0.y); pk.u.y = pk2(v0.z, v0.w);
            pk.u.z = pk2(v1.x, v1.y); pk.u.w = pk2(v1.z, v1.w);
            afrag[ks] = pk.s;
        }
    }
    // ---- prologue: stage B[0] (linear async copy, swizzle pre-baked) ----
    const char* Bpanel = (const char*)(Bn + (size_t)g * 1024 * 128);
    #pragma unroll
    for (int it = 0; it < 4; ++it)
        gload16(Bpanel + it * 8192 + tid * 16, (char*)Blds[0] + it * 8192 + tid * 16);
    __syncthreads();

    // B read addressing: row j = wc*64 + ni*32 + jl; swizzled chunk byte =
    // (ks*32 + hi*16) ^ ((jl&7)<<4)
    const int swz = (jl & 7) << 4;
    const int rb0 = (wc * 64 + jl) * 256;        // ni=0 row byte
    const int rb1 = (wc * 64 + 32 + jl) * 256;   // ni=1 row byte

    int cur = 0;
    for (int t = 0; t < 8; ++t) {
        // issue next B tile (4 loads/thread; in flight across compute+stores)
        if (t < 7) {
            const char* src = Bpanel + (size_t)(t + 1) * 32768;
            char* dst = (char*)Blds[cur ^ 1];
            #pragma unroll
            for (int it = 0; it < 4; ++it)
                gload16(src + it * 8192 + tid * 16, dst + it * 8192 + tid * 16);
        }
        asm volatile("" ::: "memory");

        const char* Bb = (const char*)Blds[cur];
        f32x16 acc0 = {0.f}, acc1 = {0.f};
        #pragma unroll
        for (int ks = 0; ks < 8; ++ks) {
            int kb = (ks * 32 + hi * 16) ^ swz;
            s16x8 b0 = *(const s16x8*)(Bb + rb0 + kb);
            s16x8 b1 = *(const s16x8*)(Bb + rb1 + kb);
            acc0 = __builtin_amdgcn_mfma_f32_32x32x16_bf16(afrag[ks], b0, acc0, 0, 0, 0);
            acc1 = __builtin_amdgcn_mfma_f32_32x32x16_bf16(afrag[ks], b1, acc1, 0, 0, 0);
        }

        // ---- stores: nontemporal; each inst = 2 full 128B lines ----
        float* obase = out + (size_t)(m0 + wr * 32 + 4 * hi) * OUT_STRIDE
                     + g * 1024 + t * 128 + wc * 64 + jl;
        #pragma unroll
        for (int reg = 0; reg < 16; ++reg) {
            int row = (reg & 3) + 8 * (reg >> 2);
            float* p = obase + (size_t)row * OUT_STRIDE;
            __builtin_nontemporal_store(acc0[reg], p);
            __builtin_nontemporal_store(acc1[reg], p + 32);
        }

        if (t < 7) {
            // 4 prefetch loads are older than the 32 stores: vmcnt(32) => loads done
            asm volatile("s_waitcnt vmcnt(32)" ::: "memory");
            __builtin_amdgcn_s_barrier();
        }
        cur ^= 1;
    }
}

extern "C" void kernel_launch(void* const* d_in, const int* in_sizes, int n_in,
                              void* d_out, int out_size, void* d_ws, size_t ws_size,
                              hipStream_t stream) {
    const float* x = (const float*)d_in[0];
    const float* V = (const float*)d_in[1];
    // d_in[2] (tile_idx) unused: index pattern computed analytically in-kernel.
    float* out = (float*)d_out;
    unsigned short* Bn = (unsigned short*)d_ws;  // 16.8 MB scratch

    const int N = in_sizes[0] / D_DIM;           // 2048
    const int nmb = N / 128;                     // 16

    vnorm_kernel<<<1024, 256, 0, stream>>>(V, Bn);
    gemm_kernel<<<dim3(nmb, 64), 512, 0, stream>>>(x, Bn, out);
}

// Round 7
// 146.455 us; speedup vs baseline: 1.3722x; 1.0037x over previous
//
#include <hip/hip_runtime.h>
#include <hip/hip_bf16.h>

typedef short s16x8 __attribute__((ext_vector_type(8)));
typedef float f32x16 __attribute__((ext_vector_type(16)));

#define D_DIM 4096
#define OUT_STRIDE 65536  // M*B = 1024*64

__device__ __forceinline__ unsigned int f2bf(float f) {
    unsigned int u = __float_as_uint(f);
    u += 0x7FFFu + ((u >> 16) & 1u);
    return u >> 16;
}
__device__ __forceinline__ unsigned int pk2(float a, float b) {
    return f2bf(a) | (f2bf(b) << 16);
}

// One block per (g,e): normalize V[g,e,:,:] over t, write bf16 B^T LINEAR:
// Bn[(g*1024 + e*64 + b)*128 + k]  (consumed into registers -> no swizzle)
__global__ __launch_bounds__(256) void vnorm_kernel(const float* __restrict__ V,
                                                    unsigned short* __restrict__ Bn) {
    const int blk = blockIdx.x;          // g*16 + e
    const int tid = threadIdx.x;
    const float* Vt = V + (size_t)blk * 8192;   // [t=128][b=64] fp32
    __shared__ float tile[8192];
    __shared__ float part[256];
    __shared__ float rnorm[64];

    for (int i = tid; i < 2048; i += 256)
        ((float4*)tile)[i] = ((const float4*)Vt)[i];
    __syncthreads();

    {
        int b = tid & 63, q = tid >> 6;
        float s = 0.f;
        for (int t = q; t < 128; t += 4) { float v = tile[t * 64 + b]; s += v * v; }
        part[tid] = s;
    }
    __syncthreads();
    if (tid < 64) {
        float tot = part[tid] + part[tid + 64] + part[tid + 128] + part[tid + 192];
        rnorm[tid] = rsqrtf(tot);
    }
    __syncthreads();

    unsigned short* rowbase = Bn + (size_t)blk * 64 * 128;  // row j = blk*64 + b
    for (int iter = 0; iter < 4; ++iter) {
        int idx = iter * 256 + tid;
        int b = idx >> 4, k8 = idx & 15;     // k8 = 16B chunk (8 bf16)
        float rn = rnorm[b];
        unsigned int w[4];
        int tb = k8 * 8;
        #pragma unroll
        for (int j = 0; j < 4; ++j) {
            float v0 = tile[(tb + 2 * j) * 64 + b] * rn;
            float v1 = tile[(tb + 2 * j + 1) * 64 + b] * rn;
            w[j] = pk2(v0, v1);
        }
        uint4* dst = (uint4*)(rowbase + b * 128) + k8;   // linear
        *dst = make_uint4(w[0], w[1], w[2], w[3]);
    }
}

// grid: (g=64 fast, mtile=N/128 slow), 1024 threads / 16 waves, 1 block/CU.
// Wave wv owns cols wv*64..+64 (2 n-frags of 32); B register-resident for the
// whole block (loaded once from linear Bn). A staged once to LDS (swizzled).
// 4 row-sub iterations of {8 ds_read_b128, 16 mfma_32x32x16, 32 stores}.
// All 16 waves write the same 32 rows' full 4KB g-chunk together, and the
// g-fast grid makes resident blocks cover full 256KB row spans concurrently
// -> DRAM page-friendly write stream. One barrier total; no vmcnt coupling.
__global__ __launch_bounds__(1024, 4) void gemm_kernel(const float* __restrict__ x,
                                                       const unsigned short* __restrict__ Bn,
                                                       float* __restrict__ out) {
    const int g = blockIdx.x;
    const int m0 = blockIdx.y * 128;
    const int tid = threadIdx.x;
    const int lane = tid & 63, wv = tid >> 6;    // 16 waves
    const int jl = lane & 31, hi = lane >> 5;

    __shared__ __align__(16) unsigned short Alds[16384];  // 32KB [r128][k128] swz

    // ---- B -> registers (2 nf x 8 ks x 16B), linear Bn, reused all 4 rsubs ----
    s16x8 bfrag[2][8];
    {
        const char* Bbase = (const char*)(Bn + (size_t)g * 131072);
        #pragma unroll
        for (int nf = 0; nf < 2; ++nf) {
            const char* rb = Bbase + (wv * 64 + nf * 32 + jl) * 256 + hi * 16;
            #pragma unroll
            for (int ks = 0; ks < 8; ++ks)
                bfrag[nf][ks] = *(const s16x8*)(rb + ks * 32);
        }
    }

    // ---- stage A once: x(fp32) -> bf16 -> LDS, XOR-swizzled for b128 reads ----
    #pragma unroll
    for (int p = 0; p < 2; ++p) {
        int c = tid + p * 1024;              // chunk id: 128 rows x 16 chunks
        int r = c >> 4, kc = c & 15;
        int k0 = kc * 8;
        int idx = (g < 32) ? (g * 128 + k0)
                           : ((k0 >> 5) * 1024 + (g - 32) * 32 + (k0 & 31));
        const float* xp = x + (size_t)(m0 + r) * D_DIM + idx;
        float4 v0 = *(const float4*)xp;
        float4 v1 = *(const float4*)(xp + 4);
        uint4 w = make_uint4(pk2(v0.x, v0.y), pk2(v0.z, v0.w),
                             pk2(v1.x, v1.y), pk2(v1.z, v1.w));
        *(uint4*)((char*)Alds + r * 256 + ((kc * 16) ^ ((r & 7) << 4))) = w;
    }
    __syncthreads();   // the only barrier

    const int swz = (jl & 7) << 4;
    #pragma unroll
    for (int rs = 0; rs < 4; ++rs) {
        const char* Ab = (const char*)Alds + (rs * 32 + jl) * 256;
        f32x16 acc0 = {0.f}, acc1 = {0.f};
        #pragma unroll
        for (int ks = 0; ks < 8; ++ks) {
            s16x8 a = *(const s16x8*)(Ab + ((ks * 32 + hi * 16) ^ swz));
            acc0 = __builtin_amdgcn_mfma_f32_32x32x16_bf16(a, bfrag[0][ks], acc0, 0, 0, 0);
            acc1 = __builtin_amdgcn_mfma_f32_32x32x16_bf16(a, bfrag[1][ks], acc1, 0, 0, 0);
        }
        // stores: lanes 0..31 of each reg = one full 128B line (x2 n-frags)
        float* obase = out + (size_t)(m0 + rs * 32 + 4 * hi) * OUT_STRIDE
                     + g * 1024 + wv * 64 + jl;
        #pragma unroll
        for (int reg = 0; reg < 16; ++reg) {
            int row = (reg & 3) + 8 * (reg >> 2);
            float* p = obase + (size_t)row * OUT_STRIDE;
            __builtin_nontemporal_store(acc0[reg], p);
            __builtin_nontemporal_store(acc1[reg], p + 32);
        }
    }
}

extern "C" void kernel_launch(void* const* d_in, const int* in_sizes, int n_in,
                              void* d_out, int out_size, void* d_ws, size_t ws_size,
                              hipStream_t stream) {
    const float* x = (const float*)d_in[0];
    const float* V = (const float*)d_in[1];
    // d_in[2] (tile_idx) unused: index pattern computed analytically in-kernel.
    float* out = (float*)d_out;
    unsigned short* Bn = (unsigned short*)d_ws;  // 16.8 MB scratch

    const int N = in_sizes[0] / D_DIM;           // 2048
    const int nmt = N / 128;                     // 16

    vnorm_kernel<<<1024, 256, 0, stream>>>(V, Bn);
    gemm_kernel<<<dim3(64, nmt), 1024, 0, stream>>>(x, Bn, out);
}

// Round 8
// 141.060 us; speedup vs baseline: 1.4247x; 1.0382x over previous
//
#include <hip/hip_runtime.h>
#include <hip/hip_bf16.h>

typedef short s16x8 __attribute__((ext_vector_type(8)));
typedef float f32x16 __attribute__((ext_vector_type(16)));

#define D_DIM 4096
#define OUT_STRIDE 65536  // M*B = 1024*64

__device__ __forceinline__ unsigned int f2bf(float f) {
    unsigned int u = __float_as_uint(f);
    u += 0x7FFFu + ((u >> 16) & 1u);
    return u >> 16;
}
__device__ __forceinline__ unsigned int pk2(float a, float b) {
    return f2bf(a) | (f2bf(b) << 16);
}

// One block per (g,e): normalize V[g,e,:,:] over t, write bf16 B^T LINEAR:
// Bn[(g*1024 + e*64 + b)*128 + k]  (consumed into registers -> no swizzle)
__global__ __launch_bounds__(256) void vnorm_kernel(const float* __restrict__ V,
                                                    unsigned short* __restrict__ Bn) {
    const int blk = blockIdx.x;          // g*16 + e
    const int tid = threadIdx.x;
    const float* Vt = V + (size_t)blk * 8192;   // [t=128][b=64] fp32
    __shared__ float tile[8192];
    __shared__ float part[256];
    __shared__ float rnorm[64];

    for (int i = tid; i < 2048; i += 256)
        ((float4*)tile)[i] = ((const float4*)Vt)[i];
    __syncthreads();

    {
        int b = tid & 63, q = tid >> 6;
        float s = 0.f;
        for (int t = q; t < 128; t += 4) { float v = tile[t * 64 + b]; s += v * v; }
        part[tid] = s;
    }
    __syncthreads();
    if (tid < 64) {
        float tot = part[tid] + part[tid + 64] + part[tid + 128] + part[tid + 192];
        rnorm[tid] = rsqrtf(tot);
    }
    __syncthreads();

    unsigned short* rowbase = Bn + (size_t)blk * 64 * 128;  // row j = blk*64 + b
    for (int iter = 0; iter < 4; ++iter) {
        int idx = iter * 256 + tid;
        int b = idx >> 4, k8 = idx & 15;     // k8 = 16B chunk (8 bf16)
        float rn = rnorm[b];
        unsigned int w[4];
        int tb = k8 * 8;
        #pragma unroll
        for (int j = 0; j < 4; ++j) {
            float v0 = tile[(tb + 2 * j) * 64 + b] * rn;
            float v1 = tile[(tb + 2 * j + 1) * 64 + b] * rn;
            w[j] = pk2(v0, v1);
        }
        uint4* dst = (uint4*)(rowbase + b * 128) + k8;   // linear
        *dst = make_uint4(w[0], w[1], w[2], w[3]);
    }
}

// grid: (s=4 fast, g=64), 256 blocks = 1/CU, 1024 threads / 16 waves.
// Block (s,g): rows s*512..+512, all 1024 cols of panel g. B register-resident
// (read ONCE per block -> Bn HBM traffic is O(1) in m, not O(epochs); the
// 512MB write stream flushes the memory-side L3, so re-reads were real HBM).
// A double-buffered in LDS, 1 barrier per 128-row chunk; stores = full lines.
__global__ __launch_bounds__(1024, 4) void gemm_kernel(const float* __restrict__ x,
                                                       const unsigned short* __restrict__ Bn,
                                                       float* __restrict__ out) {
    const int s = blockIdx.x;
    const int g = blockIdx.y;
    const int tid = threadIdx.x;
    const int lane = tid & 63, wv = tid >> 6;    // 16 waves
    const int jl = lane & 31, hi = lane >> 5;
    const int m_base = s * 512;

    __shared__ __align__(16) unsigned short Alds[2][16384];  // 2x32KB [r128][k128] swz

    // ---- B -> registers (2 nf x 8 ks x 16B), linear Bn, reused for 512 rows ----
    s16x8 bfrag[2][8];
    {
        const char* Bbase = (const char*)(Bn + (size_t)g * 131072);
        #pragma unroll
        for (int nf = 0; nf < 2; ++nf) {
            const char* rb = Bbase + (wv * 64 + nf * 32 + jl) * 256 + hi * 16;
            #pragma unroll
            for (int ks = 0; ks < 8; ++ks)
                bfrag[nf][ks] = *(const s16x8*)(rb + ks * 32);
        }
    }

    const int swz = (jl & 7) << 4;

    // ---- stage macro: 128 rows x 128 k of x -> bf16 -> Alds[buf] (swizzled) ----
    #define STAGE(MC, BUF)                                                        \
        {                                                                         \
            _Pragma("unroll")                                                     \
            for (int p = 0; p < 2; ++p) {                                         \
                int c = tid + p * 1024;                                           \
                int r = c >> 4, kc = c & 15;                                      \
                int k0 = kc * 8;                                                  \
                int idx = (g < 32) ? (g * 128 + k0)                               \
                                   : ((k0 >> 5) * 1024 + (g - 32) * 32 + (k0 & 31)); \
                const float* xp = x + (size_t)(m_base + (MC) * 128 + r) * D_DIM + idx; \
                float4 v0 = *(const float4*)xp;                                   \
                float4 v1 = *(const float4*)(xp + 4);                             \
                uint4 w = make_uint4(pk2(v0.x, v0.y), pk2(v0.z, v0.w),            \
                                     pk2(v1.x, v1.y), pk2(v1.z, v1.w));           \
                *(uint4*)((char*)Alds[BUF] + r * 256 + ((kc * 16) ^ ((r & 7) << 4))) = w; \
            }                                                                     \
        }

    STAGE(0, 0);

    #pragma unroll
    for (int mc = 0; mc < 4; ++mc) {
        __syncthreads();   // Alds[mc&1] ready; other buffer free for staging
        if (mc < 3) STAGE(mc + 1, (mc + 1) & 1);

        const char* Acur = (const char*)Alds[mc & 1];
        const int m0 = m_base + mc * 128;
        #pragma unroll
        for (int rs = 0; rs < 4; ++rs) {
            const char* Ab = Acur + (rs * 32 + jl) * 256;
            f32x16 acc0 = {0.f}, acc1 = {0.f};
            #pragma unroll
            for (int ks = 0; ks < 8; ++ks) {
                s16x8 a = *(const s16x8*)(Ab + ((ks * 32 + hi * 16) ^ swz));
                acc0 = __builtin_amdgcn_mfma_f32_32x32x16_bf16(a, bfrag[0][ks], acc0, 0, 0, 0);
                acc1 = __builtin_amdgcn_mfma_f32_32x32x16_bf16(a, bfrag[1][ks], acc1, 0, 0, 0);
            }
            // stores: lanes 0..31 of each reg = one full 128B line (x2 n-frags)
            float* obase = out + (size_t)(m0 + rs * 32 + 4 * hi) * OUT_STRIDE
                         + g * 1024 + wv * 64 + jl;
            #pragma unroll
            for (int reg = 0; reg < 16; ++reg) {
                int row = (reg & 3) + 8 * (reg >> 2);
                float* p = obase + (size_t)row * OUT_STRIDE;
                __builtin_nontemporal_store(acc0[reg], p);
                __builtin_nontemporal_store(acc1[reg], p + 32);
            }
        }
    }
    #undef STAGE
}

extern "C" void kernel_launch(void* const* d_in, const int* in_sizes, int n_in,
                              void* d_out, int out_size, void* d_ws, size_t ws_size,
                              hipStream_t stream) {
    const float* x = (const float*)d_in[0];
    const float* V = (const float*)d_in[1];
    // d_in[2] (tile_idx) unused: index pattern computed analytically in-kernel.
    float* out = (float*)d_out;
    unsigned short* Bn = (unsigned short*)d_ws;  // 16.8 MB scratch

    const int N = in_sizes[0] / D_DIM;           // 2048
    const int nsplit = N / 512;                  // 4

    vnorm_kernel<<<1024, 256, 0, stream>>>(V, Bn);
    gemm_kernel<<<dim3(nsplit, 64), 1024, 0, stream>>>(x, Bn, out);
}

// Round 9
// 140.872 us; speedup vs baseline: 1.4266x; 1.0013x over previous
//
#include <hip/hip_runtime.h>
#include <hip/hip_bf16.h>

typedef short s16x8 __attribute__((ext_vector_type(8)));
typedef float f32x16 __attribute__((ext_vector_type(16)));

#define D_DIM 4096
#define OUT_STRIDE 65536  // M*B = 1024*64

__device__ __forceinline__ unsigned int f2bf(float f) {
    unsigned int u = __float_as_uint(f);
    u += 0x7FFFu + ((u >> 16) & 1u);
    return u >> 16;
}
__device__ __forceinline__ unsigned int pk2(float a, float b) {
    return f2bf(a) | (f2bf(b) << 16);
}

// One block per (g,e): normalize V[g,e,:,:] over t, write bf16 B^T LINEAR:
// Bn[(g*1024 + e*64 + b)*128 + k]  (consumed into registers -> no swizzle)
__global__ __launch_bounds__(256) void vnorm_kernel(const float* __restrict__ V,
                                                    unsigned short* __restrict__ Bn) {
    const int blk = blockIdx.x;          // g*16 + e
    const int tid = threadIdx.x;
    const float* Vt = V + (size_t)blk * 8192;   // [t=128][b=64] fp32
    __shared__ float tile[8192];
    __shared__ float part[256];
    __shared__ float rnorm[64];

    for (int i = tid; i < 2048; i += 256)
        ((float4*)tile)[i] = ((const float4*)Vt)[i];
    __syncthreads();

    {
        int b = tid & 63, q = tid >> 6;
        float s = 0.f;
        for (int t = q; t < 128; t += 4) { float v = tile[t * 64 + b]; s += v * v; }
        part[tid] = s;
    }
    __syncthreads();
    if (tid < 64) {
        float tot = part[tid] + part[tid + 64] + part[tid + 128] + part[tid + 192];
        rnorm[tid] = rsqrtf(tot);
    }
    __syncthreads();

    unsigned short* rowbase = Bn + (size_t)blk * 64 * 128;  // row j = blk*64 + b
    for (int iter = 0; iter < 4; ++iter) {
        int idx = iter * 256 + tid;
        int b = idx >> 4, k8 = idx & 15;     // k8 = 16B chunk (8 bf16)
        float rn = rnorm[b];
        unsigned int w[4];
        int tb = k8 * 8;
        #pragma unroll
        for (int j = 0; j < 4; ++j) {
            float v0 = tile[(tb + 2 * j) * 64 + b] * rn;
            float v1 = tile[(tb + 2 * j + 1) * 64 + b] * rn;
            w[j] = pk2(v0, v1);
        }
        uint4* dst = (uint4*)(rowbase + b * 128) + k8;   // linear
        *dst = make_uint4(w[0], w[1], w[2], w[3]);
    }
}

// grid: (s=4 fast, g=64), 256 blocks = 1/CU, 1024 threads / 16 waves.
// Block (s,g): rows s*512..+512, all 1024 cols of panel g. B register-resident.
// A double-buffered in LDS. KEY CHANGE vs R8: the inter-chunk barrier is
// lgkmcnt(0)+s_barrier (LDS ordering only) instead of __syncthreads(), whose
// implicit vmcnt(0) drained ~512KB of NT stores per chunk with nothing to
// hide it at 1 block/CU. Stores now pipeline across chunk boundaries.
__global__ __launch_bounds__(1024, 4) void gemm_kernel(const float* __restrict__ x,
                                                       const unsigned short* __restrict__ Bn,
                                                       float* __restrict__ out) {
    const int s = blockIdx.x;
    const int g = blockIdx.y;
    const int tid = threadIdx.x;
    const int lane = tid & 63, wv = tid >> 6;    // 16 waves
    const int jl = lane & 31, hi = lane >> 5;
    const int m_base = s * 512;

    __shared__ __align__(16) unsigned short Alds[2][16384];  // 2x32KB [r128][k128] swz

    // ---- B -> registers (2 nf x 8 ks x 16B), linear Bn, reused for 512 rows ----
    s16x8 bfrag[2][8];
    {
        const char* Bbase = (const char*)(Bn + (size_t)g * 131072);
        #pragma unroll
        for (int nf = 0; nf < 2; ++nf) {
            const char* rb = Bbase + (wv * 64 + nf * 32 + jl) * 256 + hi * 16;
            #pragma unroll
            for (int ks = 0; ks < 8; ++ks)
                bfrag[nf][ks] = *(const s16x8*)(rb + ks * 32);
        }
    }

    const int swz = (jl & 7) << 4;

    // ---- stage macro: 128 rows x 128 k of x -> bf16 -> Alds[buf] (swizzled) ----
    #define STAGE(MC, BUF)                                                        \
        {                                                                         \
            _Pragma("unroll")                                                     \
            for (int p = 0; p < 2; ++p) {                                         \
                int c = tid + p * 1024;                                           \
                int r = c >> 4, kc = c & 15;                                      \
                int k0 = kc * 8;                                                  \
                int idx = (g < 32) ? (g * 128 + k0)                               \
                                   : ((k0 >> 5) * 1024 + (g - 32) * 32 + (k0 & 31)); \
                const float* xp = x + (size_t)(m_base + (MC) * 128 + r) * D_DIM + idx; \
                float4 v0 = *(const float4*)xp;                                   \
                float4 v1 = *(const float4*)(xp + 4);                             \
                uint4 w = make_uint4(pk2(v0.x, v0.y), pk2(v0.z, v0.w),            \
                                     pk2(v1.x, v1.y), pk2(v1.z, v1.w));           \
                *(uint4*)((char*)Alds[BUF] + r * 256 + ((kc * 16) ^ ((r & 7) << 4))) = w; \
            }                                                                     \
        }

    STAGE(0, 0);

    #pragma unroll
    for (int mc = 0; mc < 4; ++mc) {
        // LDS-only barrier: ds_writes (STAGE) ordered; do NOT drain the store
        // queue (no vmcnt) -> output writes pipeline across chunks.
        asm volatile("s_waitcnt lgkmcnt(0)" ::: "memory");
        __builtin_amdgcn_s_barrier();
        asm volatile("" ::: "memory");

        if (mc < 3) STAGE(mc + 1, (mc + 1) & 1);

        const char* Acur = (const char*)Alds[mc & 1];
        const int m0 = m_base + mc * 128;
        #pragma unroll
        for (int rs = 0; rs < 4; ++rs) {
            const char* Ab = Acur + (rs * 32 + jl) * 256;
            f32x16 acc0 = {0.f}, acc1 = {0.f};
            #pragma unroll
            for (int ks = 0; ks < 8; ++ks) {
                s16x8 a = *(const s16x8*)(Ab + ((ks * 32 + hi * 16) ^ swz));
                acc0 = __builtin_amdgcn_mfma_f32_32x32x16_bf16(a, bfrag[0][ks], acc0, 0, 0, 0);
                acc1 = __builtin_amdgcn_mfma_f32_32x32x16_bf16(a, bfrag[1][ks], acc1, 0, 0, 0);
            }
            // stores: lanes 0..31 of each reg = one full 128B line (x2 n-frags)
            float* obase = out + (size_t)(m0 + rs * 32 + 4 * hi) * OUT_STRIDE
                         + g * 1024 + wv * 64 + jl;
            #pragma unroll
            for (int reg = 0; reg < 16; ++reg) {
                int row = (reg & 3) + 8 * (reg >> 2);
                float* p = obase + (size_t)row * OUT_STRIDE;
                __builtin_nontemporal_store(acc0[reg], p);
                __builtin_nontemporal_store(acc1[reg], p + 32);
            }
        }
    }
    #undef STAGE
}

extern "C" void kernel_launch(void* const* d_in, const int* in_sizes, int n_in,
                              void* d_out, int out_size, void* d_ws, size_t ws_size,
                              hipStream_t stream) {
    const float* x = (const float*)d_in[0];
    const float* V = (const float*)d_in[1];
    // d_in[2] (tile_idx) unused: index pattern computed analytically in-kernel.
    float* out = (float*)d_out;
    unsigned short* Bn = (unsigned short*)d_ws;  // 16.8 MB scratch

    const int N = in_sizes[0] / D_DIM;           // 2048
    const int nsplit = N / 512;                  // 4

    vnorm_kernel<<<1024, 256, 0, stream>>>(V, Bn);
    gemm_kernel<<<dim3(nsplit, 64), 1024, 0, stream>>>(x, Bn, out);
}